// Round 15
// baseline (200.402 us; speedup 1.0000x reference)
//
#include <hip/hip_runtime.h>
#include <hip/hip_bf16.h>
#include <stdint.h>

#define HID 1024
#define NH 16
#define DH 64
#define SEQ 2048
#define NB 4
#define MTOT (NB*SEQ)   // 8192
#define SM_SCALE 0.18033688f   // 0.125 * log2(e)

typedef __attribute__((ext_vector_type(4))) float f32x4;
typedef __attribute__((ext_vector_type(16))) float f32x16;
typedef __attribute__((ext_vector_type(8))) __bf16 bf16x8;
typedef __attribute__((ext_vector_type(4))) __bf16 bf16x4;
typedef __attribute__((ext_vector_type(2))) __bf16 bf16x2;
typedef __attribute__((ext_vector_type(2))) int i32x2;

__device__ __forceinline__ f32x4 mfma16(bf16x8 a, bf16x8 b, f32x4 c) {
    return __builtin_amdgcn_mfma_f32_16x16x32_bf16(a, b, c, 0, 0, 0);
}
__device__ __forceinline__ f32x16 mfma32(bf16x8 a, bf16x8 b, f32x16 c) {
    return __builtin_amdgcn_mfma_f32_32x32x16_bf16(a, b, c, 0, 0, 0);
}

__device__ __forceinline__ void gload16(const void* g, void* l) {
    __builtin_amdgcn_global_load_lds(
        (const __attribute__((address_space(1))) unsigned int*)g,
        (__attribute__((address_space(3))) unsigned int*)l, 16, 0, 0);
}

__device__ __forceinline__ float fexp2(float x) {
#if __has_builtin(__builtin_amdgcn_exp2f)
    return __builtin_amdgcn_exp2f(x);
#else
    return exp2f(x);
#endif
}

__device__ __forceinline__ unsigned pkbf2(float lo, float hi) {
    union { bf16x2 v; unsigned u; } c;
    c.v = (bf16x2){ (__bf16)lo, (__bf16)hi };
    return c.u;
}

__device__ __forceinline__ void swap32(unsigned &a, unsigned &b) {
#if __has_builtin(__builtin_amdgcn_permlane32_swap)
    i32x2 r = __builtin_amdgcn_permlane32_swap((int)a, (int)b, false, false);
    a = (unsigned)r.x; b = (unsigned)r.y;
#else
    const bool hi = (threadIdx.x & 32) != 0;
    unsigned ta = __shfl_xor(a, 32), tb = __shfl_xor(b, 32);
    unsigned na = hi ? tb : a;
    unsigned nb = hi ? b : ta;
    a = na; b = nb;
#endif
}

// ---------------- fused fp32 -> bf16 convert (8 elem/thread) ----------------
__global__ __launch_bounds__(256)
void cvt5(const float* __restrict__ X,  const float* __restrict__ Wq,
          const float* __restrict__ Wk, const float* __restrict__ Wv,
          const float* __restrict__ Wp,
          __bf16* __restrict__ Xb,  __bf16* __restrict__ Wqb,
          __bf16* __restrict__ Wkb, __bf16* __restrict__ Wvb,
          __bf16* __restrict__ Wpb)
{
    const float* src; __bf16* dst; int n;
    switch (blockIdx.y) {
        case 0:  src = X;  dst = Xb;  n = MTOT * HID; break;
        case 1:  src = Wq; dst = Wqb; n = HID * HID;  break;
        case 2:  src = Wk; dst = Wkb; n = HID * HID;  break;
        case 3:  src = Wv; dst = Wvb; n = HID * HID;  break;
        default: src = Wp; dst = Wpb; n = HID * HID;  break;
    }
    const int stride = gridDim.x * 256 * 8;
    for (int i = (blockIdx.x * 256 + threadIdx.x) * 8; i < n; i += stride) {
        float4 v0 = *(const float4*)(src + i);
        float4 v1 = *(const float4*)(src + i + 4);
        bf16x8 o = { (__bf16)v0.x, (__bf16)v0.y, (__bf16)v0.z, (__bf16)v0.w,
                     (__bf16)v1.x, (__bf16)v1.y, (__bf16)v1.z, (__bf16)v1.w };
        *(bf16x8*)(dst + i) = o;
    }
}

// ====== single-phase counted-vmcnt GEMM: 256x128 tile, BK=64, ring-3 LDS ======
template<int PROJ>
__global__ __launch_bounds__(512, 1)
void gemm8(const __bf16* __restrict__ A,
           const __bf16* __restrict__ Wq, const __bf16* __restrict__ Wk,
           const __bf16* __restrict__ Wv,
           const float* __restrict__ bq, const float* __restrict__ bk,
           const float* __restrict__ bv, const float* __restrict__ hz,
           __bf16* __restrict__ Qo, __bf16* __restrict__ Ko,
           __bf16* __restrict__ Vo, float* __restrict__ Po)
{
    __shared__ __bf16 As[3][256 * 64];   // 32KB per slot
    __shared__ __bf16 Bs[3][128 * 64];   // 16KB per slot
    const int tid = threadIdx.x, lane = tid & 63, wid = tid >> 6;
    const int m0 = blockIdx.x * 256, n0 = blockIdx.y * 128;
    const int wr = wid >> 1, wc = wid & 1;
    const int mode = PROJ ? 3 : (int)blockIdx.z;

    const __bf16* W    = PROJ ? Wq : (mode == 0 ? Wq : mode == 1 ? Wk : Wv);
    const float*  bias = PROJ ? bq : (mode == 0 ? bq : mode == 1 ? bk : bv);

    const int cA0 = tid, cA1 = tid + 512, cA2 = tid + 1024, cA3 = tid + 1536;
    const int cB0 = tid, cB1 = tid + 512;
    const __bf16* aA0 = A + (size_t)(m0 + (cA0 >> 3)) * HID + ((cA0 & 7) ^ ((cA0 >> 3) & 7)) * 8;
    const __bf16* aA1 = A + (size_t)(m0 + (cA1 >> 3)) * HID + ((cA1 & 7) ^ ((cA1 >> 3) & 7)) * 8;
    const __bf16* aA2 = A + (size_t)(m0 + (cA2 >> 3)) * HID + ((cA2 & 7) ^ ((cA2 >> 3) & 7)) * 8;
    const __bf16* aA3 = A + (size_t)(m0 + (cA3 >> 3)) * HID + ((cA3 & 7) ^ ((cA3 >> 3) & 7)) * 8;
    const __bf16* bB0 = W + (size_t)(n0 + (cB0 >> 3)) * HID + ((cB0 & 7) ^ ((cB0 >> 3) & 7)) * 8;
    const __bf16* bB1 = W + (size_t)(n0 + (cB1 >> 3)) * HID + ((cB1 & 7) ^ ((cB1 >> 3) & 7)) * 8;

#define STAGE_AB(sl, j) do { char* da_ = (char*)&As[sl][0]; char* db_ = (char*)&Bs[sl][0]; \
    int kk_ = (j) * 64;                                                                    \
    gload16(aA0 + kk_, da_ + cA0 * 16); gload16(aA1 + kk_, da_ + cA1 * 16);                \
    gload16(aA2 + kk_, da_ + cA2 * 16); gload16(aA3 + kk_, da_ + cA3 * 16);                \
    gload16(bB0 + kk_, db_ + cB0 * 16); gload16(bB1 + kk_, db_ + cB1 * 16); } while (0)

    f32x4 acc[4][4];
    #pragma unroll
    for (int i = 0; i < 4; i++)
        #pragma unroll
        for (int j = 0; j < 4; j++) acc[i][j] = (f32x4){0.f, 0.f, 0.f, 0.f};

    const int la = lane & 15, lk = lane >> 4;

    STAGE_AB(0, 0);
    STAGE_AB(1, 1);
    asm volatile("s_waitcnt vmcnt(6)" ::: "memory");
    __builtin_amdgcn_s_barrier();

    int slc = 0;
    for (int j = 0; j < 16; ++j) {
        const char* Ab = (const char*)&As[slc][0];
        const char* Bb = (const char*)&Bs[slc][0];
        const int js = j + 2;
        const int sls = slc == 0 ? 2 : slc - 1;   // slot (j+2)%3

        bf16x8 af[4][2], bf[4][2];
        #pragma unroll
        for (int mi = 0; mi < 4; mi++)
            #pragma unroll
            for (int ks = 0; ks < 2; ks++) {
                int row = wr * 64 + mi * 16 + la;
                af[mi][ks] = *(const bf16x8*)(Ab + row * 128 +
                    ((ks * 64 + lk * 16) ^ ((row & 7) << 4)));
            }
        #pragma unroll
        for (int ni = 0; ni < 4; ni++)
            #pragma unroll
            for (int ks = 0; ks < 2; ks++) {
                int row = wc * 64 + ni * 16 + la;
                bf[ni][ks] = *(const bf16x8*)(Bb + row * 128 +
                    ((ks * 64 + lk * 16) ^ ((row & 7) << 4)));
            }

        if (js < 16) STAGE_AB(sls, js);

        __builtin_amdgcn_s_setprio(1);
        #pragma unroll
        for (int mi = 0; mi < 4; mi++)
            #pragma unroll
            for (int ni = 0; ni < 4; ni++) {
                acc[mi][ni] = mfma16(af[mi][0], bf[ni][0], acc[mi][ni]);
                acc[mi][ni] = mfma16(af[mi][1], bf[ni][1], acc[mi][ni]);
            }
        __builtin_amdgcn_s_setprio(0);

        if (j < 13)       { asm volatile("s_waitcnt vmcnt(6)" ::: "memory"); }
        else if (j == 14) { asm volatile("s_waitcnt vmcnt(0)" ::: "memory"); }
        __builtin_amdgcn_s_barrier();

        slc = slc == 2 ? 0 : slc + 1;
    }
#undef STAGE_AB

    if (PROJ) {
        #pragma unroll
        for (int mi = 0; mi < 4; mi++)
            #pragma unroll
            for (int ni = 0; ni < 4; ni++)
                #pragma unroll
                for (int r = 0; r < 4; r++) {
                    int m = m0 + wr * 64 + mi * 16 + lk * 4 + r;
                    int n = n0 + wc * 64 + ni * 16 + la;
                    Po[(size_t)m * HID + n] = (acc[mi][ni][r] + bias[n]) * hz[n];
                }
    } else if (mode == 2) {
        #pragma unroll
        for (int mi = 0; mi < 4; mi++)
            #pragma unroll
            for (int ni = 0; ni < 4; ni++) {
                int m = m0 + wr * 64 + mi * 16 + lk * 4;
                int n = n0 + wc * 64 + ni * 16 + la;
                int b = m >> 11, s = m & (SEQ - 1);
                int h = n >> 6,  d = n & 63;
                bf16x4 o;
                #pragma unroll
                for (int r = 0; r < 4; r++) o[r] = (__bf16)(acc[mi][ni][r] + bias[n]);
                *(bf16x4*)(Vo + ((size_t)(b * NH + h) * DH + d) * SEQ + s) = o;
            }
    } else {
        const float qs = (mode == 0) ? SM_SCALE : 1.0f;
        __bf16* Og = (mode == 0) ? Qo : Ko;
        #pragma unroll
        for (int mi = 0; mi < 4; mi++)
            #pragma unroll
            for (int ni = 0; ni < 4; ni++)
                #pragma unroll
                for (int r = 0; r < 4; r++) {
                    int m = m0 + wr * 64 + mi * 16 + lk * 4 + r;
                    int n = n0 + wc * 64 + ni * 16 + la;
                    float v = (acc[mi][ni][r] + bias[n]) * qs;
                    int b = m >> 11, s = m & (SEQ - 1);
                    int h = n >> 6,  d = n & 63;
                    Og[((size_t)(b * NH + h) * SEQ + s) * DH + d] = (__bf16)v;
                }
    }
}

// ------- flash attention: KVB=128, 256B-row tiles, NO-MAX softmax -------
// VALU-diet version: persistent zero f32x16 kills per-tile st zero-init;
// XOR-base addressing ( r0*256 + (co^kx) == (r0*256+kx)^co since bit ranges
// are disjoint ) kills per-read add; row+32 read folds +8192 into ds imm.
#define KVB 128

__global__ __launch_bounds__(512, 4)
void attn(const __bf16* __restrict__ Q, const __bf16* __restrict__ K,
          const __bf16* __restrict__ VT, const float* __restrict__ heads_z,
          __bf16* __restrict__ C)
{
    __shared__ __bf16 Ks[2][64 * 128];   // 16KB each
    __shared__ __bf16 Vs[2][64 * 128];   // 16KB each
    const int tid = threadIdx.x, lane = tid & 63, wid = tid >> 6;
    const int lh = lane >> 5;
    const int id = blockIdx.x;
    const int bh = (id & 7) | ((id >> 6) << 3);   // bijective: bh&7 = id&7 -> same XCD
    const int qb = (id >> 3) & 7;
    const int b = bh >> 4, hd = bh & 15;
    const __bf16* Qg = Q + (size_t)bh * SEQ * DH;
    const __bf16* Kg = K + (size_t)bh * SEQ * DH;
    const __bf16* Vg = VT + (size_t)bh * DH * SEQ;
    const int q = qb * 256 + wid * 32 + (lane & 31);
    const int r0 = lane & 31;
    const int kx = (r0 & 15) << 4;   // 16-slot row-XOR (256B rows)
    const unsigned rbase = r0 * 256 + kx;   // per-lane tile byte base

    bf16x8 ones8;
    #pragma unroll
    for (int j = 0; j < 8; j++) ones8[j] = (__bf16)1.0f;

    // persistent zero accumulator source (16 VGPRs; LDS is the occupancy limit)
    f32x16 zv;
    #pragma unroll
    for (int r = 0; r < 16; r++) zv[r] = 0.f;

    bf16x8 qf[4];
    #pragma unroll
    for (int s = 0; s < 4; s++)
        qf[s] = *(const bf16x8*)(Qg + (size_t)q * DH + s * 16 + lh * 8);

    f32x16 ctx0, ctx1;
    #pragma unroll
    for (int r = 0; r < 16; r++) { ctx0[r] = 0.f; ctx1[r] = 0.f; }
    float lrun = 0.f;

    const int kr = tid >> 4;
    const int ks = (tid & 15) ^ (kr & 15);
    const int kda = (ks & 7) * 8;
    const int kvA = kr + ((ks >> 3) << 6);
    const int kvB = kvA + 32;

#define STAGE(buf, kv0_) do {                                                         \
    char* dk_ = (char*)&Ks[buf][0]; char* dv_ = (char*)&Vs[buf][0];                   \
    gload16(Kg + (size_t)((kv0_) + kvA) * DH + kda, dk_ + tid * 16);                  \
    gload16(Kg + (size_t)((kv0_) + kvB) * DH + kda, dk_ + tid * 16 + 8192);           \
    gload16(Vg + (size_t)kr * SEQ + (kv0_) + ks * 8, dv_ + tid * 16);                 \
    gload16(Vg + (size_t)(kr + 32) * SEQ + (kv0_) + ks * 8, dv_ + tid * 16 + 8192);   \
} while (0)

    STAGE(0, 0);
    __syncthreads();

    int cur = 0;
    for (int kv0 = 0; kv0 < SEQ; kv0 += KVB) {
        if (kv0 + KVB < SEQ) STAGE(cur ^ 1, kv0 + KVB);

        const uintptr_t kbp = (uintptr_t)&Ks[cur][0] + rbase;
        const uintptr_t vbp = (uintptr_t)&Vs[cur][0] + rbase;

        #pragma unroll
        for (int hh = 0; hh < 2; hh++) {
            // --- QK^T: st[kv][q] (log2 domain, pre-scaled); first MFMA seeds from zv ---
            f32x16 st0, st1;
            __builtin_amdgcn_s_setprio(1);
            {
                unsigned co = (unsigned)((hh * 8 + lh) << 4);
                const char* ka = (const char*)(kbp ^ co);
                st0 = mfma32(*(const bf16x8*)ka, qf[0], zv);
                st1 = mfma32(*(const bf16x8*)(ka + 8192), qf[0], zv);
            }
            #pragma unroll
            for (int s = 1; s < 4; s++) {
                unsigned co = (unsigned)((hh * 8 + 2 * s + lh) << 4);
                const char* ka = (const char*)(kbp ^ co);
                st0 = mfma32(*(const bf16x8*)ka, qf[s], st0);
                st1 = mfma32(*(const bf16x8*)(ka + 8192), qf[s], st1);
            }
            __builtin_amdgcn_s_setprio(0);

            // --- direct exp2, no max tracking (scores bounded by construction) ---
            #pragma unroll
            for (int r = 0; r < 16; r++) {
                st0[r] = fexp2(st0[r]);
                st1[r] = fexp2(st1[r]);
            }

            // --- P -> PV B-fragments in-register (T12 exchange) ---
            unsigned X0 = pkbf2(st0[0],  st0[1]),  X1 = pkbf2(st0[2],  st0[3]);
            unsigned X2 = pkbf2(st0[4],  st0[5]),  X3 = pkbf2(st0[6],  st0[7]);
            unsigned X4 = pkbf2(st0[8],  st0[9]),  X5 = pkbf2(st0[10], st0[11]);
            unsigned X6 = pkbf2(st0[12], st0[13]), X7 = pkbf2(st0[14], st0[15]);
            unsigned Y0 = pkbf2(st1[0],  st1[1]),  Y1 = pkbf2(st1[2],  st1[3]);
            unsigned Y2 = pkbf2(st1[4],  st1[5]),  Y3 = pkbf2(st1[6],  st1[7]);
            unsigned Y4 = pkbf2(st1[8],  st1[9]),  Y5 = pkbf2(st1[10], st1[11]);
            unsigned Y6 = pkbf2(st1[12], st1[13]), Y7 = pkbf2(st1[14], st1[15]);
            swap32(X0, X2); swap32(X1, X3);
            swap32(X4, X6); swap32(X5, X7);
            swap32(Y0, Y2); swap32(Y1, Y3);
            swap32(Y4, Y6); swap32(Y5, Y7);
            union W4 { unsigned w[4]; bf16x8 v; };
            W4 pf[4];
            pf[0].w[0]=X0; pf[0].w[1]=X1; pf[0].w[2]=X2; pf[0].w[3]=X3;
            pf[1].w[0]=X4; pf[1].w[1]=X5; pf[1].w[2]=X6; pf[1].w[3]=X7;
            pf[2].w[0]=Y0; pf[2].w[1]=Y1; pf[2].w[2]=Y2; pf[2].w[3]=Y3;
            pf[3].w[0]=Y4; pf[3].w[1]=Y5; pf[3].w[2]=Y6; pf[3].w[3]=Y7;

            // --- row-sum on the MFMA pipe (st0 dead, reuse; only [0] read) ---
            st0[0] = 0.f;
            #pragma unroll
            for (int s = 0; s < 4; s++) st0 = mfma32(ones8, pf[s].v, st0);

            // --- PV: ctx^T += V^T x P^T ---
            __builtin_amdgcn_s_setprio(1);
            #pragma unroll
            for (int s = 0; s < 4; s++) {
                unsigned co = (unsigned)((hh * 8 + 2 * s + lh) << 4);
                const char* va = (const char*)(vbp ^ co);
                ctx0 = mfma32(*(const bf16x8*)va, pf[s].v, ctx0);
                ctx1 = mfma32(*(const bf16x8*)(va + 8192), pf[s].v, ctx1);
            }
            __builtin_amdgcn_s_setprio(0);

            lrun += st0[0];
        }

        __syncthreads();
        cur ^= 1;
    }
#undef STAGE

    const float hzv = heads_z[hd];
    const float rl = hzv / lrun;
    __bf16* Crow = C + (size_t)(b * SEQ + q) * HID + hd * DH;
    #pragma unroll
    for (int g = 0; g < 4; g++) {
        bf16x4 o0, o1;
        #pragma unroll
        for (int j = 0; j < 4; j++) {
            o0[j] = (__bf16)(ctx0[4 * g + j] * rl);
            o1[j] = (__bf16)(ctx1[4 * g + j] * rl);
        }
        int d0 = 8 * g + 4 * lh;
        *(bf16x4*)(Crow + d0) = o0;
        *(bf16x4*)(Crow + 32 + d0) = o1;
    }
}

extern "C" void kernel_launch(void* const* d_in, const int* in_sizes, int n_in,
                              void* d_out, int out_size, void* d_ws, size_t ws_size,
                              hipStream_t stream)
{
    const float* X    = (const float*)d_in[0];
    const float* Wq   = (const float*)d_in[1];
    const float* bq   = (const float*)d_in[2];
    const float* Wk   = (const float*)d_in[3];
    const float* bk   = (const float*)d_in[4];
    const float* Wv   = (const float*)d_in[5];
    const float* bv   = (const float*)d_in[6];
    const float* Wp   = (const float*)d_in[7];
    const float* bp   = (const float*)d_in[8];
    const float* hz   = (const float*)d_in[9];
    const float* hidz = (const float*)d_in[10];

    __bf16* ws  = (__bf16*)d_ws;
    __bf16* Xb  = ws;
    __bf16* Wqb = Xb  + (size_t)MTOT * HID;
    __bf16* Wkb = Wqb + (size_t)HID * HID;
    __bf16* Wvb = Wkb + (size_t)HID * HID;
    __bf16* Wpb = Wvb + (size_t)HID * HID;
    __bf16* Qb  = Wpb + (size_t)HID * HID;
    __bf16* Kb  = Qb  + (size_t)MTOT * HID;
    __bf16* VTb = Kb  + (size_t)MTOT * HID;
    __bf16* Cb  = VTb + (size_t)MTOT * HID;

    cvt5<<<dim3(2048, 5), 256, 0, stream>>>(X, Wq, Wk, Wv, Wp, Xb, Wqb, Wkb, Wvb, Wpb);

    gemm8<0><<<dim3(MTOT / 256, HID / 128, 3), 512, 0, stream>>>(
        Xb, Wqb, Wkb, Wvb, bq, bk, bv, nullptr, Qb, Kb, VTb, nullptr);

    attn<<<dim3(512), 512, 0, stream>>>(Qb, Kb, VTb, hz, Cb);

    gemm8<1><<<dim3(MTOT / 256, HID / 128), 512, 0, stream>>>(
        Cb, Wpb, nullptr, nullptr, bp, nullptr, nullptr, hidz,
        nullptr, nullptr, nullptr, (float*)d_out);
}

// Round 16
// 178.059 us; speedup vs baseline: 1.1255x; 1.1255x over previous
//
#include <hip/hip_runtime.h>
#include <hip/hip_bf16.h>

#define HID 1024
#define NH 16
#define DH 64
#define SEQ 2048
#define NB 4
#define MTOT (NB*SEQ)   // 8192
#define SM_SCALE 0.18033688f   // 0.125 * log2(e)

typedef __attribute__((ext_vector_type(4))) float f32x4;
typedef __attribute__((ext_vector_type(16))) float f32x16;
typedef __attribute__((ext_vector_type(8))) __bf16 bf16x8;
typedef __attribute__((ext_vector_type(4))) __bf16 bf16x4;
typedef __attribute__((ext_vector_type(2))) __bf16 bf16x2;
typedef __attribute__((ext_vector_type(2))) int i32x2;

__device__ __forceinline__ f32x4 mfma16(bf16x8 a, bf16x8 b, f32x4 c) {
    return __builtin_amdgcn_mfma_f32_16x16x32_bf16(a, b, c, 0, 0, 0);
}
__device__ __forceinline__ f32x16 mfma32(bf16x8 a, bf16x8 b, f32x16 c) {
    return __builtin_amdgcn_mfma_f32_32x32x16_bf16(a, b, c, 0, 0, 0);
}

__device__ __forceinline__ void gload16(const void* g, void* l) {
    __builtin_amdgcn_global_load_lds(
        (const __attribute__((address_space(1))) unsigned int*)g,
        (__attribute__((address_space(3))) unsigned int*)l, 16, 0, 0);
}

__device__ __forceinline__ float fexp2(float x) {
#if __has_builtin(__builtin_amdgcn_exp2f)
    return __builtin_amdgcn_exp2f(x);
#else
    return exp2f(x);
#endif
}

__device__ __forceinline__ unsigned pkbf2(float lo, float hi) {
    union { bf16x2 v; unsigned u; } c;
    c.v = (bf16x2){ (__bf16)lo, (__bf16)hi };
    return c.u;
}

__device__ __forceinline__ void swap32(unsigned &a, unsigned &b) {
#if __has_builtin(__builtin_amdgcn_permlane32_swap)
    i32x2 r = __builtin_amdgcn_permlane32_swap((int)a, (int)b, false, false);
    a = (unsigned)r.x; b = (unsigned)r.y;
#else
    const bool hi = (threadIdx.x & 32) != 0;
    unsigned ta = __shfl_xor(a, 32), tb = __shfl_xor(b, 32);
    unsigned na = hi ? tb : a;
    unsigned nb = hi ? b : ta;
    a = na; b = nb;
#endif
}

// ---------------- fused fp32 -> bf16 convert (8 elem/thread) ----------------
__global__ __launch_bounds__(256)
void cvt5(const float* __restrict__ X,  const float* __restrict__ Wq,
          const float* __restrict__ Wk, const float* __restrict__ Wv,
          const float* __restrict__ Wp,
          __bf16* __restrict__ Xb,  __bf16* __restrict__ Wqb,
          __bf16* __restrict__ Wkb, __bf16* __restrict__ Wvb,
          __bf16* __restrict__ Wpb)
{
    const float* src; __bf16* dst; int n;
    switch (blockIdx.y) {
        case 0:  src = X;  dst = Xb;  n = MTOT * HID; break;
        case 1:  src = Wq; dst = Wqb; n = HID * HID;  break;
        case 2:  src = Wk; dst = Wkb; n = HID * HID;  break;
        case 3:  src = Wv; dst = Wvb; n = HID * HID;  break;
        default: src = Wp; dst = Wpb; n = HID * HID;  break;
    }
    const int stride = gridDim.x * 256 * 8;
    for (int i = (blockIdx.x * 256 + threadIdx.x) * 8; i < n; i += stride) {
        float4 v0 = *(const float4*)(src + i);
        float4 v1 = *(const float4*)(src + i + 4);
        bf16x8 o = { (__bf16)v0.x, (__bf16)v0.y, (__bf16)v0.z, (__bf16)v0.w,
                     (__bf16)v1.x, (__bf16)v1.y, (__bf16)v1.z, (__bf16)v1.w };
        *(bf16x8*)(dst + i) = o;
    }
}

// ====== single-phase counted-vmcnt GEMM: 256x128 tile, BK=64, ring-3 LDS ======
template<int PROJ>
__global__ __launch_bounds__(512, 1)
void gemm8(const __bf16* __restrict__ A,
           const __bf16* __restrict__ Wq, const __bf16* __restrict__ Wk,
           const __bf16* __restrict__ Wv,
           const float* __restrict__ bq, const float* __restrict__ bk,
           const float* __restrict__ bv, const float* __restrict__ hz,
           __bf16* __restrict__ Qo, __bf16* __restrict__ Ko,
           __bf16* __restrict__ Vo, float* __restrict__ Po)
{
    __shared__ __bf16 As[3][256 * 64];   // 32KB per slot
    __shared__ __bf16 Bs[3][128 * 64];   // 16KB per slot
    const int tid = threadIdx.x, lane = tid & 63, wid = tid >> 6;
    const int m0 = blockIdx.x * 256, n0 = blockIdx.y * 128;
    const int wr = wid >> 1, wc = wid & 1;
    const int mode = PROJ ? 3 : (int)blockIdx.z;

    const __bf16* W    = PROJ ? Wq : (mode == 0 ? Wq : mode == 1 ? Wk : Wv);
    const float*  bias = PROJ ? bq : (mode == 0 ? bq : mode == 1 ? bk : bv);

    const int cA0 = tid, cA1 = tid + 512, cA2 = tid + 1024, cA3 = tid + 1536;
    const int cB0 = tid, cB1 = tid + 512;
    const __bf16* aA0 = A + (size_t)(m0 + (cA0 >> 3)) * HID + ((cA0 & 7) ^ ((cA0 >> 3) & 7)) * 8;
    const __bf16* aA1 = A + (size_t)(m0 + (cA1 >> 3)) * HID + ((cA1 & 7) ^ ((cA1 >> 3) & 7)) * 8;
    const __bf16* aA2 = A + (size_t)(m0 + (cA2 >> 3)) * HID + ((cA2 & 7) ^ ((cA2 >> 3) & 7)) * 8;
    const __bf16* aA3 = A + (size_t)(m0 + (cA3 >> 3)) * HID + ((cA3 & 7) ^ ((cA3 >> 3) & 7)) * 8;
    const __bf16* bB0 = W + (size_t)(n0 + (cB0 >> 3)) * HID + ((cB0 & 7) ^ ((cB0 >> 3) & 7)) * 8;
    const __bf16* bB1 = W + (size_t)(n0 + (cB1 >> 3)) * HID + ((cB1 & 7) ^ ((cB1 >> 3) & 7)) * 8;

#define STAGE_AB(sl, j) do { char* da_ = (char*)&As[sl][0]; char* db_ = (char*)&Bs[sl][0]; \
    int kk_ = (j) * 64;                                                                    \
    gload16(aA0 + kk_, da_ + cA0 * 16); gload16(aA1 + kk_, da_ + cA1 * 16);                \
    gload16(aA2 + kk_, da_ + cA2 * 16); gload16(aA3 + kk_, da_ + cA3 * 16);                \
    gload16(bB0 + kk_, db_ + cB0 * 16); gload16(bB1 + kk_, db_ + cB1 * 16); } while (0)

    f32x4 acc[4][4];
    #pragma unroll
    for (int i = 0; i < 4; i++)
        #pragma unroll
        for (int j = 0; j < 4; j++) acc[i][j] = (f32x4){0.f, 0.f, 0.f, 0.f};

    const int la = lane & 15, lk = lane >> 4;

    STAGE_AB(0, 0);
    STAGE_AB(1, 1);
    asm volatile("s_waitcnt vmcnt(6)" ::: "memory");
    __builtin_amdgcn_s_barrier();

    int slc = 0;
    for (int j = 0; j < 16; ++j) {
        const char* Ab = (const char*)&As[slc][0];
        const char* Bb = (const char*)&Bs[slc][0];
        const int js = j + 2;
        const int sls = slc == 0 ? 2 : slc - 1;   // slot (j+2)%3

        bf16x8 af[4][2], bf[4][2];
        #pragma unroll
        for (int mi = 0; mi < 4; mi++)
            #pragma unroll
            for (int ks = 0; ks < 2; ks++) {
                int row = wr * 64 + mi * 16 + la;
                af[mi][ks] = *(const bf16x8*)(Ab + row * 128 +
                    ((ks * 64 + lk * 16) ^ ((row & 7) << 4)));
            }
        #pragma unroll
        for (int ni = 0; ni < 4; ni++)
            #pragma unroll
            for (int ks = 0; ks < 2; ks++) {
                int row = wc * 64 + ni * 16 + la;
                bf[ni][ks] = *(const bf16x8*)(Bb + row * 128 +
                    ((ks * 64 + lk * 16) ^ ((row & 7) << 4)));
            }

        if (js < 16) STAGE_AB(sls, js);

        __builtin_amdgcn_s_setprio(1);
        #pragma unroll
        for (int mi = 0; mi < 4; mi++)
            #pragma unroll
            for (int ni = 0; ni < 4; ni++) {
                acc[mi][ni] = mfma16(af[mi][0], bf[ni][0], acc[mi][ni]);
                acc[mi][ni] = mfma16(af[mi][1], bf[ni][1], acc[mi][ni]);
            }
        __builtin_amdgcn_s_setprio(0);

        if (j < 13)       { asm volatile("s_waitcnt vmcnt(6)" ::: "memory"); }
        else if (j == 14) { asm volatile("s_waitcnt vmcnt(0)" ::: "memory"); }
        __builtin_amdgcn_s_barrier();

        slc = slc == 2 ? 0 : slc + 1;
    }
#undef STAGE_AB

    if (PROJ) {
        #pragma unroll
        for (int mi = 0; mi < 4; mi++)
            #pragma unroll
            for (int ni = 0; ni < 4; ni++)
                #pragma unroll
                for (int r = 0; r < 4; r++) {
                    int m = m0 + wr * 64 + mi * 16 + lk * 4 + r;
                    int n = n0 + wc * 64 + ni * 16 + la;
                    Po[(size_t)m * HID + n] = (acc[mi][ni][r] + bias[n]) * hz[n];
                }
    } else if (mode == 2) {
        #pragma unroll
        for (int mi = 0; mi < 4; mi++)
            #pragma unroll
            for (int ni = 0; ni < 4; ni++) {
                int m = m0 + wr * 64 + mi * 16 + lk * 4;
                int n = n0 + wc * 64 + ni * 16 + la;
                int b = m >> 11, s = m & (SEQ - 1);
                int h = n >> 6,  d = n & 63;
                bf16x4 o;
                #pragma unroll
                for (int r = 0; r < 4; r++) o[r] = (__bf16)(acc[mi][ni][r] + bias[n]);
                *(bf16x4*)(Vo + ((size_t)(b * NH + h) * DH + d) * SEQ + s) = o;
            }
    } else {
        const float qs = (mode == 0) ? SM_SCALE : 1.0f;
        __bf16* Og = (mode == 0) ? Qo : Ko;
        #pragma unroll
        for (int mi = 0; mi < 4; mi++)
            #pragma unroll
            for (int ni = 0; ni < 4; ni++)
                #pragma unroll
                for (int r = 0; r < 4; r++) {
                    int m = m0 + wr * 64 + mi * 16 + lk * 4 + r;
                    int n = n0 + wc * 64 + ni * 16 + la;
                    float v = (acc[mi][ni][r] + bias[n]) * qs;
                    int b = m >> 11, s = m & (SEQ - 1);
                    int h = n >> 6,  d = n & 63;
                    Og[((size_t)(b * NH + h) * SEQ + s) * DH + d] = (__bf16)v;
                }
    }
}

// ------- flash attention: KVB=128, 256B-row tiles, NO-MAX softmax -------
// R14-proven addressing (char* from __shared__, r0*256 + co) + persistent-zero
// C-in seeding for the QK MFMA chain (kills 32 v_mov zero-inits per half-tile).
#define KVB 128

__global__ __launch_bounds__(512, 4)
void attn(const __bf16* __restrict__ Q, const __bf16* __restrict__ K,
          const __bf16* __restrict__ VT, const float* __restrict__ heads_z,
          __bf16* __restrict__ C)
{
    __shared__ __bf16 Ks[2][64 * 128];   // 16KB each
    __shared__ __bf16 Vs[2][64 * 128];   // 16KB each
    const int tid = threadIdx.x, lane = tid & 63, wid = tid >> 6;
    const int lh = lane >> 5;
    const int id = blockIdx.x;
    const int bh = (id & 7) | ((id >> 6) << 3);   // bijective: bh&7 = id&7 -> same XCD
    const int qb = (id >> 3) & 7;
    const int b = bh >> 4, hd = bh & 15;
    const __bf16* Qg = Q + (size_t)bh * SEQ * DH;
    const __bf16* Kg = K + (size_t)bh * SEQ * DH;
    const __bf16* Vg = VT + (size_t)bh * DH * SEQ;
    const int q = qb * 256 + wid * 32 + (lane & 31);
    const int r0 = lane & 31;
    const int kx = (r0 & 15) << 4;   // 16-slot row-XOR (256B rows)

    bf16x8 ones8;
    #pragma unroll
    for (int j = 0; j < 8; j++) ones8[j] = (__bf16)1.0f;

    // persistent zero C-in source (16 VGPRs; occupancy is LDS-bound, not VGPR-bound)
    f32x16 zv;
    #pragma unroll
    for (int r = 0; r < 16; r++) zv[r] = 0.f;

    bf16x8 qf[4];
    #pragma unroll
    for (int s = 0; s < 4; s++)
        qf[s] = *(const bf16x8*)(Qg + (size_t)q * DH + s * 16 + lh * 8);

    f32x16 ctx0, ctx1;
    #pragma unroll
    for (int r = 0; r < 16; r++) { ctx0[r] = 0.f; ctx1[r] = 0.f; }
    float lrun = 0.f;

    const int kr = tid >> 4;
    const int ks = (tid & 15) ^ (kr & 15);
    const int kda = (ks & 7) * 8;
    const int kvA = kr + ((ks >> 3) << 6);
    const int kvB = kvA + 32;

#define STAGE(buf, kv0_) do {                                                         \
    char* dk_ = (char*)&Ks[buf][0]; char* dv_ = (char*)&Vs[buf][0];                   \
    gload16(Kg + (size_t)((kv0_) + kvA) * DH + kda, dk_ + tid * 16);                  \
    gload16(Kg + (size_t)((kv0_) + kvB) * DH + kda, dk_ + tid * 16 + 8192);           \
    gload16(Vg + (size_t)kr * SEQ + (kv0_) + ks * 8, dv_ + tid * 16);                 \
    gload16(Vg + (size_t)(kr + 32) * SEQ + (kv0_) + ks * 8, dv_ + tid * 16 + 8192);   \
} while (0)

    STAGE(0, 0);
    __syncthreads();

    int cur = 0;
    for (int kv0 = 0; kv0 < SEQ; kv0 += KVB) {
        if (kv0 + KVB < SEQ) STAGE(cur ^ 1, kv0 + KVB);

        #pragma unroll
        for (int hh = 0; hh < 2; hh++) {
            const char* Kb = (const char*)&Ks[cur][0];
            const char* Vb = (const char*)&Vs[cur][0];

            // --- QK^T: first MFMA seeds from zv (no per-tile zero-init) ---
            f32x16 st0, st1;
            __builtin_amdgcn_s_setprio(1);
            {
                int co = (((hh * 8 + lh) << 4)) ^ kx;
                st0 = mfma32(*(const bf16x8*)(Kb + r0 * 256 + co), qf[0], zv);
                st1 = mfma32(*(const bf16x8*)(Kb + (r0 + 32) * 256 + co), qf[0], zv);
            }
            #pragma unroll
            for (int s = 1; s < 4; s++) {
                int co = (((hh * 8 + 2 * s + lh) << 4)) ^ kx;
                bf16x8 k0 = *(const bf16x8*)(Kb + r0 * 256 + co);
                bf16x8 k1 = *(const bf16x8*)(Kb + (r0 + 32) * 256 + co);
                st0 = mfma32(k0, qf[s], st0);
                st1 = mfma32(k1, qf[s], st1);
            }
            __builtin_amdgcn_s_setprio(0);

            #pragma unroll
            for (int r = 0; r < 16; r++) {
                st0[r] = fexp2(st0[r]);
                st1[r] = fexp2(st1[r]);
            }

            unsigned X0 = pkbf2(st0[0],  st0[1]),  X1 = pkbf2(st0[2],  st0[3]);
            unsigned X2 = pkbf2(st0[4],  st0[5]),  X3 = pkbf2(st0[6],  st0[7]);
            unsigned X4 = pkbf2(st0[8],  st0[9]),  X5 = pkbf2(st0[10], st0[11]);
            unsigned X6 = pkbf2(st0[12], st0[13]), X7 = pkbf2(st0[14], st0[15]);
            unsigned Y0 = pkbf2(st1[0],  st1[1]),  Y1 = pkbf2(st1[2],  st1[3]);
            unsigned Y2 = pkbf2(st1[4],  st1[5]),  Y3 = pkbf2(st1[6],  st1[7]);
            unsigned Y4 = pkbf2(st1[8],  st1[9]),  Y5 = pkbf2(st1[10], st1[11]);
            unsigned Y6 = pkbf2(st1[12], st1[13]), Y7 = pkbf2(st1[14], st1[15]);
            swap32(X0, X2); swap32(X1, X3);
            swap32(X4, X6); swap32(X5, X7);
            swap32(Y0, Y2); swap32(Y1, Y3);
            swap32(Y4, Y6); swap32(Y5, Y7);
            union W4 { unsigned w[4]; bf16x8 v; };
            W4 pf[4];
            pf[0].w[0]=X0; pf[0].w[1]=X1; pf[0].w[2]=X2; pf[0].w[3]=X3;
            pf[1].w[0]=X4; pf[1].w[1]=X5; pf[1].w[2]=X6; pf[1].w[3]=X7;
            pf[2].w[0]=Y0; pf[2].w[1]=Y1; pf[2].w[2]=Y2; pf[2].w[3]=Y3;
            pf[3].w[0]=Y4; pf[3].w[1]=Y5; pf[3].w[2]=Y6; pf[3].w[3]=Y7;

            // --- row-sum on the MFMA pipe: seed from zv, read [0] only ---
            st0 = mfma32(ones8, pf[0].v, zv);
            #pragma unroll
            for (int s = 1; s < 4; s++) st0 = mfma32(ones8, pf[s].v, st0);

            __builtin_amdgcn_s_setprio(1);
            #pragma unroll
            for (int s = 0; s < 4; s++) {
                int co = (((hh * 8 + 2 * s + lh) << 4)) ^ kx;
                bf16x8 v0 = *(const bf16x8*)(Vb + r0 * 256 + co);
                bf16x8 v1 = *(const bf16x8*)(Vb + (r0 + 32) * 256 + co);
                ctx0 = mfma32(v0, pf[s].v, ctx0);
                ctx1 = mfma32(v1, pf[s].v, ctx1);
            }
            __builtin_amdgcn_s_setprio(0);

            lrun += st0[0];
        }

        __syncthreads();
        cur ^= 1;
    }
#undef STAGE

    const float hzv = heads_z[hd];
    const float rl = hzv / lrun;
    __bf16* Crow = C + (size_t)(b * SEQ + q) * HID + hd * DH;
    #pragma unroll
    for (int g = 0; g < 4; g++) {
        bf16x4 o0, o1;
        #pragma unroll
        for (int j = 0; j < 4; j++) {
            o0[j] = (__bf16)(ctx0[4 * g + j] * rl);
            o1[j] = (__bf16)(ctx1[4 * g + j] * rl);
        }
        int d0 = 8 * g + 4 * lh;
        *(bf16x4*)(Crow + d0) = o0;
        *(bf16x4*)(Crow + 32 + d0) = o1;
    }
}

extern "C" void kernel_launch(void* const* d_in, const int* in_sizes, int n_in,
                              void* d_out, int out_size, void* d_ws, size_t ws_size,
                              hipStream_t stream)
{
    const float* X    = (const float*)d_in[0];
    const float* Wq   = (const float*)d_in[1];
    const float* bq   = (const float*)d_in[2];
    const float* Wk   = (const float*)d_in[3];
    const float* bk   = (const float*)d_in[4];
    const float* Wv   = (const float*)d_in[5];
    const float* bv   = (const float*)d_in[6];
    const float* Wp   = (const float*)d_in[7];
    const float* bp   = (const float*)d_in[8];
    const float* hz   = (const float*)d_in[9];
    const float* hidz = (const float*)d_in[10];

    __bf16* ws  = (__bf16*)d_ws;
    __bf16* Xb  = ws;
    __bf16* Wqb = Xb  + (size_t)MTOT * HID;
    __bf16* Wkb = Wqb + (size_t)HID * HID;
    __bf16* Wvb = Wkb + (size_t)HID * HID;
    __bf16* Wpb = Wvb + (size_t)HID * HID;
    __bf16* Qb  = Wpb + (size_t)HID * HID;
    __bf16* Kb  = Qb  + (size_t)MTOT * HID;
    __bf16* VTb = Kb  + (size_t)MTOT * HID;
    __bf16* Cb  = VTb + (size_t)MTOT * HID;

    cvt5<<<dim3(2048, 5), 256, 0, stream>>>(X, Wq, Wk, Wv, Wp, Xb, Wqb, Wkb, Wvb, Wpb);

    gemm8<0><<<dim3(MTOT / 256, HID / 128, 3), 512, 0, stream>>>(
        Xb, Wqb, Wkb, Wvb, bq, bk, bv, nullptr, Qb, Kb, VTb, nullptr);

    attn<<<dim3(512), 512, 0, stream>>>(Qb, Kb, VTb, hz, Cb);

    gemm8<1><<<dim3(MTOT / 256, HID / 128), 512, 0, stream>>>(
        Cb, Wpb, nullptr, nullptr, bp, nullptr, nullptr, hidz,
        nullptr, nullptr, nullptr, (float*)d_out);
}